// Round 7
// baseline (2648.916 us; speedup 1.0000x reference)
//
#include <hip/hip_runtime.h>

#define D       256
#define DH      32
#define FFDIM   1024
#define VOCAB   2048
#define GENLEN  16
#define BATCH   8
#define NSLOT   7
#define TF      17
#define NLAYER  4

#define SCOPE_AGENT __HIP_MEMORY_SCOPE_AGENT

typedef float    f32x4 __attribute__((ext_vector_type(4)));
typedef unsigned u32x4 __attribute__((ext_vector_type(4)));

struct Params {
  const float *slots, *W_slot_proj, *dict_emb, *pe;
  const float *ln_self_w, *ln_self_b, *Wq_s, *Wk_s, *Wv_s, *Wo_s;
  const float *ln_cross_w, *ln_cross_b, *Wq_c, *Wk_c, *Wv_c, *Wo_c;
  const float *ln_ffn_w, *ln_ffn_b, *W1, *b1, *W2, *b2;
  const float *ln_f_w, *ln_f_b, *W_out;
  float *enc, *P0, *P1, *tri;
  unsigned *flags;
  float *out_z, *out_lp;
};

__device__ __forceinline__ float cload(const float* p) {
  return __hip_atomic_load(p, __ATOMIC_RELAXED, SCOPE_AGENT);
}
__device__ __forceinline__ void cstore(float* p, float v) {
  __hip_atomic_store(p, v, __ATOMIC_RELAXED, SCOPE_AGENT);
}

__device__ __forceinline__ float blockSum(float v, float* red) {
  #pragma unroll
  for (int o = 32; o > 0; o >>= 1) v += __shfl_down(v, o);
  const int lane = threadIdx.x & 63, w = threadIdx.x >> 6;
  if (lane == 0) red[w] = v;
  __syncthreads();
  float s = red[0] + red[1] + red[2] + red[3];
  __syncthreads();
  return s;
}

__global__ __launch_bounds__(256, 1) void mega_kernel(Params p)
{
  const int blk = blockIdx.x;
  const int bb = blk >> 3, sl = blk & 7, tid = threadIdx.x;
  unsigned* flags = p.flags + bb * 256;   // 1 KB apart per batch group
  unsigned target = 0;

  __shared__ __align__(16) float hsh[D];
  __shared__ __align__(16) float ash[128];
  __shared__ float qsh[DH], osh[DH], score[TF], red[4];
  __shared__ float sval[256];
  __shared__ int   sidx[256];
  __shared__ float stage[NSLOT * D];
  __shared__ float kls[NLAYER][TF][DH + 1], vls[NLAYER][TF][DH + 1];
  __shared__ float kcls[NLAYER][NSLOT][DH + 1], vcls[NLAYER][NSLOT][DH + 1];

  // ---- stage boundary: drain stores, publish arrival flag (no fetch_add chain) ----
  auto gsync = [&]() {
    __syncthreads();                  // drains all waves' vmem (partials at LLC)
    ++target;
    if (tid == 0)
      __hip_atomic_store(flags + sl, target, __ATOMIC_RELAXED, SCOPE_AGENT);
  };
  // ---- wide poll: all 8 flags in 2 loads, single wait ----
  auto gwait = [&]() {
    u32x4 f0, f1;
    for (;;) {
      asm volatile(
        "global_load_dwordx4 %0, %2, off sc0 sc1\n\t"
        "global_load_dwordx4 %1, %2, off offset:16 sc0 sc1\n\t"
        "s_waitcnt vmcnt(0)"
        : "=&v"(f0), "=&v"(f1) : "v"(flags) : "memory");
      if (f0.x >= target && f0.y >= target && f0.z >= target && f0.w >= target &&
          f1.x >= target && f1.y >= target && f1.z >= target && f1.w >= target)
        break;
      __builtin_amdgcn_s_sleep(1);
    }
  };

  auto layernorm = [&](float xv, const float* w, const float* b) -> float {
    const float mean = blockSum(xv, red) * (1.f / D);
    const float dv = xv - mean;
    const float var = blockSum(dv * dv, red) * (1.f / D);
    return dv * (1.f / sqrtf(var + 1e-5f)) * w[tid] + b[tid];
  };

  // ---- fold: 8 coherent loads in one asm block, one wait (parallel RTs) ----
  auto fold8 = [&](const float* P) -> float {
    const float* a0 = P + (bb * 8 + 0) * D + tid;
    const float* a4 = P + (bb * 8 + 4) * D + tid;
    float s0, s1, s2, s3, s4, s5, s6, s7;
    asm volatile(
      "global_load_dword %0, %8, off sc0 sc1\n\t"
      "global_load_dword %1, %8, off offset:1024 sc0 sc1\n\t"
      "global_load_dword %2, %8, off offset:2048 sc0 sc1\n\t"
      "global_load_dword %3, %8, off offset:3072 sc0 sc1\n\t"
      "global_load_dword %4, %9, off sc0 sc1\n\t"
      "global_load_dword %5, %9, off offset:1024 sc0 sc1\n\t"
      "global_load_dword %6, %9, off offset:2048 sc0 sc1\n\t"
      "global_load_dword %7, %9, off offset:3072 sc0 sc1\n\t"
      "s_waitcnt vmcnt(0)"
      : "=&v"(s0), "=&v"(s1), "=&v"(s2), "=&v"(s3),
        "=&v"(s4), "=&v"(s5), "=&v"(s6), "=&v"(s7)
      : "v"(a0), "v"(a4));
    return ((s0 + s1) + (s2 + s3)) + ((s4 + s5) + (s6 + s7));
  };

  float heldLogit = 0.f;
  int   lastAmax  = 0;

  // ---- tri combine: 8 x dwordx4 in one asm block (parallel), then reg math ----
  auto consume_tri = [&](int row) {
    const float* tb = p.tri + bb * 64;
    f32x4 q0,q1,q2,q3,q4,q5,q6,q7;
    asm volatile(
      "global_load_dwordx4 %0, %8, off sc0 sc1\n\t"
      "global_load_dwordx4 %1, %8, off offset:32 sc0 sc1\n\t"
      "global_load_dwordx4 %2, %8, off offset:64 sc0 sc1\n\t"
      "global_load_dwordx4 %3, %8, off offset:96 sc0 sc1\n\t"
      "global_load_dwordx4 %4, %8, off offset:128 sc0 sc1\n\t"
      "global_load_dwordx4 %5, %8, off offset:160 sc0 sc1\n\t"
      "global_load_dwordx4 %6, %8, off offset:192 sc0 sc1\n\t"
      "global_load_dwordx4 %7, %8, off offset:224 sc0 sc1\n\t"
      "s_waitcnt vmcnt(0)"
      : "=&v"(q0), "=&v"(q1), "=&v"(q2), "=&v"(q3),
        "=&v"(q4), "=&v"(q5), "=&v"(q6), "=&v"(q7)
      : "v"(tb));
    float gm = q0.x;
    gm = fmaxf(gm, q1.x); gm = fmaxf(gm, q2.x); gm = fmaxf(gm, q3.x);
    gm = fmaxf(gm, q4.x); gm = fmaxf(gm, q5.x); gm = fmaxf(gm, q6.x); gm = fmaxf(gm, q7.x);
    float gs = 0.f; float best = -1e30f; int am = 0;
    const f32x4 qa[8] = {q0,q1,q2,q3,q4,q5,q6,q7};
    #pragma unroll
    for (int j = 0; j < 8; ++j) {
      gs += qa[j].y * expf(qa[j].x - gm);
      if (qa[j].x > best) { best = qa[j].x; am = j * 256 + (int)qa[j].z; }  // first-index ties
    }
    const float lse = gm + logf(gs);
    p.out_lp[(bb * GENLEN + row) * VOCAB + sl * 256 + tid] = heldLogit - lse;
    if (sl == 0 && tid == 0)
      p.out_z[bb * VOCAB * GENLEN + am * GENLEN + row] = 1.0f;
    lastAmax = am;
  };

  // ================= init: enc = slots @ W_slot_proj (cols sl*32..) =================
  if (tid < 32) {
    const int c = sl * 32 + tid;
    float acc[NSLOT] = {0.f,0.f,0.f,0.f,0.f,0.f,0.f};
    #pragma unroll 8
    for (int i = 0; i < D; ++i) {
      const float w = p.W_slot_proj[i * D + c];
      #pragma unroll
      for (int s = 0; s < NSLOT; ++s) acc[s] += p.slots[(bb * NSLOT + s) * D + i] * w;
    }
    for (int s = 0; s < NSLOT; ++s) cstore(&p.enc[(bb * NSLOT + s) * D + c], acc[s]);
  }
  gsync(); gwait();

  // ============ init: cross K/V for this block's head -> LDS (block-local) ============
  {
    for (int i = tid; i < NSLOT * D; i += 256) stage[i] = cload(&p.enc[bb * NSLOT * D + i]);
    __syncthreads();
    const int l = tid >> 6, g = tid & 63, c32 = g >> 1, mat = g & 1;
    const float* W = (mat ? p.Wv_c : p.Wk_c) + l * D * D + sl * DH + c32;
    float acc[NSLOT] = {0.f,0.f,0.f,0.f,0.f,0.f,0.f};
    #pragma unroll 8
    for (int i = 0; i < D; ++i) {
      const float w = W[i * D];
      #pragma unroll
      for (int s = 0; s < NSLOT; ++s) acc[s] += stage[s * D + i] * w;
    }
    if (mat) { for (int s = 0; s < NSLOT; ++s) vcls[l][s][c32] = acc[s]; }
    else     { for (int s = 0; s < NSLOT; ++s) kcls[l][s][c32] = acc[s]; }
    __syncthreads();
  }

  float* Pbuf[2] = {p.P0, p.P1};
  int par = 0;
  float x = 0.f;

  // ================================ generation loop ================================
  #pragma unroll 1
  for (int t = 0; t < GENLEN; ++t) {
    #pragma unroll 1
    for (int l = 0; l < NLAYER; ++l) {
      // ------------------------------- SELF-ATTN -------------------------------
      {
        gsync();
        // prefetch this stage's weights into regs while exchange is in flight
        float wqkv[128], wo[32];
        const int mm = tid >> 6, g = tid & 63, c32 = g >> 1, half = g & 1;
        if (tid < 192) {
          const float* W = (mm == 0 ? p.Wq_s : (mm == 1 ? p.Wk_s : p.Wv_s))
                         + l * D * D + sl * DH + c32;
          #pragma unroll
          for (int k = 0; k < 128; ++k) wqkv[k] = W[(size_t)(half * 128 + k) * D];
        }
        {
          const float* W = p.Wo_s + l * D * D + sl * DH * D + tid;
          #pragma unroll
          for (int k = 0; k < 32; ++k) wo[k] = W[(size_t)k * D];
        }
        gwait();

        if (l == 0) {
          int tok = 0;
          if (t > 0) { consume_tri(t - 1); tok = lastAmax + 1; }
          x = p.dict_emb[tok * D + tid] + p.pe[t * D + tid];
        } else {
          x += fold8(Pbuf[par]);
        }
        const float h = layernorm(x, p.ln_self_w + l * D, p.ln_self_b + l * D);
        if (l == 0) x = h;                    // SLATE quirk (replicated identically)
        hsh[tid] = h;
        __syncthreads();

        if (tid < 192) {
          float acc = 0.f;
          #pragma unroll
          for (int j = 0; j < 32; ++j) {
            const f32x4 hv = *(const f32x4*)&hsh[half * 128 + 4 * j];
            acc = fmaf(hv.x, wqkv[4 * j + 0], acc);
            acc = fmaf(hv.y, wqkv[4 * j + 1], acc);
            acc = fmaf(hv.z, wqkv[4 * j + 2], acc);
            acc = fmaf(hv.w, wqkv[4 * j + 3], acc);
          }
          acc += __shfl_xor(acc, 1);
          if (half == 0) {
            if (mm == 0)      qsh[c32] = acc * 0.17677669529663689f;   // dh^-0.5
            else if (mm == 1) kls[l][t][c32] = acc;
            else              vls[l][t][c32] = acc;
          }
        }
        __syncthreads();

        if (tid <= t) {
          float a = 0.f;
          #pragma unroll
          for (int r = 0; r < DH; ++r) a += qsh[r] * kls[l][tid][r];
          score[tid] = a;
        }
        __syncthreads();
        if (tid == 0) {
          float mx = -1e30f;
          for (int i = 0; i <= t; ++i) mx = fmaxf(mx, score[i]);
          float s2 = 0.f;
          for (int i = 0; i <= t; ++i) { const float e = expf(score[i] - mx); score[i] = e; s2 += e; }
          const float inv = 1.f / s2;
          for (int i = 0; i <= t; ++i) score[i] *= inv;
        }
        __syncthreads();
        if (tid < DH) {
          float a = 0.f;
          for (int pp = 0; pp <= t; ++pp) a += score[pp] * vls[l][pp][tid];
          osh[tid] = a;
        }
        __syncthreads();
        {
          float a0 = 0.f;
          #pragma unroll
          for (int k = 0; k < 32; ++k) a0 = fmaf(osh[k], wo[k], a0);
          cstore(&Pbuf[par ^ 1][(bb * 8 + sl) * D + tid], a0);
        }
        par ^= 1;
      }

      // ------------------------------- CROSS-ATTN -------------------------------
      {
        gsync();
        float wq[32], woc[32];
        const int c32 = tid >> 3, sub = tid & 7;
        {
          const float* W = p.Wq_c + l * D * D + sl * DH + c32;
          #pragma unroll
          for (int k = 0; k < 32; ++k) wq[k] = W[(size_t)(sub * 32 + k) * D];
        }
        {
          const float* W = p.Wo_c + l * D * D + sl * DH * D + tid;
          #pragma unroll
          for (int k = 0; k < 32; ++k) woc[k] = W[(size_t)k * D];
        }
        gwait();

        x += fold8(Pbuf[par]);
        hsh[tid] = layernorm(x, p.ln_cross_w + l * D, p.ln_cross_b + l * D);
        __syncthreads();

        {
          float acc = 0.f;
          #pragma unroll
          for (int j = 0; j < 8; ++j) {
            const f32x4 hv = *(const f32x4*)&hsh[sub * 32 + 4 * j];
            acc = fmaf(hv.x, wq[4 * j + 0], acc);
            acc = fmaf(hv.y, wq[4 * j + 1], acc);
            acc = fmaf(hv.z, wq[4 * j + 2], acc);
            acc = fmaf(hv.w, wq[4 * j + 3], acc);
          }
          acc += __shfl_xor(acc, 1);
          acc += __shfl_xor(acc, 2);
          acc += __shfl_xor(acc, 4);
          if (sub == 0) qsh[c32] = acc * 0.17677669529663689f;
        }
        __syncthreads();
        if (tid < NSLOT) {
          float a = 0.f;
          #pragma unroll
          for (int r = 0; r < DH; ++r) a += qsh[r] * kcls[l][tid][r];
          score[tid] = a;
        }
        __syncthreads();
        if (tid == 0) {
          float mx = -1e30f;
          for (int i = 0; i < NSLOT; ++i) mx = fmaxf(mx, score[i]);
          float s2 = 0.f;
          for (int i = 0; i < NSLOT; ++i) { const float e = expf(score[i] - mx); score[i] = e; s2 += e; }
          const float inv = 1.f / s2;
          for (int i = 0; i < NSLOT; ++i) score[i] *= inv;
        }
        __syncthreads();
        if (tid < DH) {
          float a = 0.f;
          #pragma unroll
          for (int s = 0; s < NSLOT; ++s) a += score[s] * vcls[l][s][tid];
          osh[tid] = a;
        }
        __syncthreads();
        {
          float a0 = 0.f;
          #pragma unroll
          for (int k = 0; k < 32; ++k) a0 = fmaf(osh[k], woc[k], a0);
          cstore(&Pbuf[par ^ 1][(bb * 8 + sl) * D + tid], a0);
        }
        par ^= 1;
      }

      // ---------------------------------- FFN ----------------------------------
      {
        gsync();
        float w1r[128], w2r[128];
        const int c128 = tid >> 1, half = tid & 1, c = sl * 128 + c128;
        {
          const float* W = p.W1 + l * D * FFDIM + c;
          #pragma unroll
          for (int k = 0; k < 128; ++k) w1r[k] = W[(size_t)(half * 128 + k) * FFDIM];
        }
        {
          const float* W = p.W2 + l * FFDIM * D + sl * 128 * D + tid;
          #pragma unroll
          for (int k = 0; k < 128; ++k) w2r[k] = W[(size_t)k * D];
        }
        gwait();

        x += fold8(Pbuf[par]);
        hsh[tid] = layernorm(x, p.ln_ffn_w + l * D, p.ln_ffn_b + l * D);
        __syncthreads();

        {
          float acc = 0.f;
          #pragma unroll
          for (int j = 0; j < 32; ++j) {
            const f32x4 hv = *(const f32x4*)&hsh[half * 128 + 4 * j];
            acc = fmaf(hv.x, w1r[4 * j + 0], acc);
            acc = fmaf(hv.y, w1r[4 * j + 1], acc);
            acc = fmaf(hv.z, w1r[4 * j + 2], acc);
            acc = fmaf(hv.w, w1r[4 * j + 3], acc);
          }
          acc += __shfl_xor(acc, 1);
          if (half == 0) ash[c128] = fmaxf(acc + p.b1[l * FFDIM + c], 0.f);
        }
        __syncthreads();
        {
          float acc = 0.f;
          #pragma unroll
          for (int j = 0; j < 32; ++j) {
            const f32x4 av = *(const f32x4*)&ash[4 * j];
            acc = fmaf(av.x, w2r[4 * j + 0], acc);
            acc = fmaf(av.y, w2r[4 * j + 1], acc);
            acc = fmaf(av.z, w2r[4 * j + 2], acc);
            acc = fmaf(av.w, w2r[4 * j + 3], acc);
          }
          if (sl == 0) acc += p.b2[l * D + tid];
          cstore(&Pbuf[par ^ 1][(bb * 8 + sl) * D + tid], acc);
        }
        par ^= 1;
      }
    }

    // --------------------------------- LOGITS ---------------------------------
    {
      gsync();
      float wout[256];
      {
        const float* W = p.W_out + sl * 256 + tid;
        #pragma unroll
        for (int k = 0; k < 256; ++k) wout[k] = W[(size_t)k * VOCAB];
      }
      gwait();

      x += fold8(Pbuf[par]);
      hsh[tid] = layernorm(x, p.ln_f_w, p.ln_f_b);
      __syncthreads();
      {
        float acc = 0.f;
        #pragma unroll
        for (int j = 0; j < 64; ++j) {
          const f32x4 hv = *(const f32x4*)&hsh[4 * j];
          acc = fmaf(hv.x, wout[4 * j + 0], acc);
          acc = fmaf(hv.y, wout[4 * j + 1], acc);
          acc = fmaf(hv.z, wout[4 * j + 2], acc);
          acc = fmaf(hv.w, wout[4 * j + 3], acc);
        }
        heldLogit = acc;
      }

      sval[tid] = heldLogit; sidx[tid] = tid;
      __syncthreads();
      for (int s = 128; s; s >>= 1) {
        if (tid < s) {
          float v2 = sval[tid + s]; int i2 = sidx[tid + s];
          if (v2 > sval[tid] || (v2 == sval[tid] && i2 < sidx[tid])) { sval[tid] = v2; sidx[tid] = i2; }
        }
        __syncthreads();
      }
      const float smax = sval[0]; const int sarg = sidx[0];
      __syncthreads();
      const float ssum = blockSum(expf(heldLogit - smax), red);
      if (tid == 0) {
        cstore(&p.tri[(bb * 8 + sl) * 8 + 0], smax);
        cstore(&p.tri[(bb * 8 + sl) * 8 + 1], ssum);
        cstore(&p.tri[(bb * 8 + sl) * 8 + 2], (float)sarg);
      }
    }
  }

  // ------------------------------ final step output ------------------------------
  gsync(); gwait();
  consume_tri(GENLEN - 1);
}

extern "C" void kernel_launch(void* const* d_in, const int* in_sizes, int n_in,
                              void* d_out, int out_size, void* d_ws, size_t ws_size,
                              hipStream_t stream)
{
  Params p;
  const float* const* in = (const float* const*)d_in;
  p.slots = in[0];  p.W_slot_proj = in[1]; p.dict_emb = in[2]; p.pe = in[3];
  p.ln_self_w = in[4];  p.ln_self_b = in[5];
  p.Wq_s = in[6];  p.Wk_s = in[7];  p.Wv_s = in[8];  p.Wo_s = in[9];
  p.ln_cross_w = in[10]; p.ln_cross_b = in[11];
  p.Wq_c = in[12]; p.Wk_c = in[13]; p.Wv_c = in[14]; p.Wo_c = in[15];
  p.ln_ffn_w = in[16]; p.ln_ffn_b = in[17];
  p.W1 = in[18]; p.b1 = in[19]; p.W2 = in[20]; p.b2 = in[21];
  p.ln_f_w = in[22]; p.ln_f_b = in[23]; p.W_out = in[24];

  p.flags = (unsigned*)d_ws;                 // 8 groups x 256 u32 (1 KB each)
  float* ws = (float*)d_ws + BATCH * 256;
  p.enc = ws;  ws += BATCH * NSLOT * D;
  p.P0  = ws;  ws += BATCH * 8 * D;
  p.P1  = ws;  ws += BATCH * 8 * D;
  p.tri = ws;  ws += BATCH * 8 * 8;

  p.out_z  = (float*)d_out;
  p.out_lp = (float*)d_out + BATCH * VOCAB * GENLEN;

  hipMemsetAsync(d_ws, 0, BATCH * 256 * sizeof(unsigned), stream);
  hipMemsetAsync(d_out, 0, (size_t)out_size * sizeof(float), stream);

  mega_kernel<<<64, 256, 0, stream>>>(p);
}

// Round 8
// 1506.578 us; speedup vs baseline: 1.7582x; 1.7582x over previous
//
#include <hip/hip_runtime.h>

#define D       256
#define DH      32
#define FFDIM   1024
#define VOCAB   2048
#define GENLEN  16
#define BATCH   8
#define NSLOT   7
#define TF      17
#define NLAYER  4

#define SCOPE_AGENT __HIP_MEMORY_SCOPE_AGENT

typedef float    f32x4 __attribute__((ext_vector_type(4)));
typedef unsigned u32x4 __attribute__((ext_vector_type(4)));

struct Params {
  const float *slots, *W_slot_proj, *dict_emb, *pe;
  const float *ln_self_w, *ln_self_b, *Wq_s, *Wk_s, *Wv_s, *Wo_s;
  const float *ln_cross_w, *ln_cross_b, *Wq_c, *Wk_c, *Wv_c, *Wo_c;
  const float *ln_ffn_w, *ln_ffn_b, *W1, *b1, *W2, *b2;
  const float *ln_f_w, *ln_f_b, *W_out;
  float *enc, *P0, *P1, *tri;
  unsigned *flags;
  float *out_z, *out_lp;
};

__device__ __forceinline__ float cload(const float* p) {
  return __hip_atomic_load(p, __ATOMIC_RELAXED, SCOPE_AGENT);
}
__device__ __forceinline__ void cstore(float* p, float v) {
  __hip_atomic_store(p, v, __ATOMIC_RELAXED, SCOPE_AGENT);
}

__device__ __forceinline__ float blockSum(float v, float* red) {
  #pragma unroll
  for (int o = 32; o > 0; o >>= 1) v += __shfl_down(v, o);
  const int lane = threadIdx.x & 63, w = threadIdx.x >> 6;
  if (lane == 0) red[w] = v;
  __syncthreads();
  float s = red[0] + red[1] + red[2] + red[3];
  __syncthreads();
  return s;
}

// ---- double-buffered streaming GEMV (live set = 64 regs, FP order == round 6) ----
template<int N>
__device__ __forceinline__ float dotStreamPre(const float* __restrict__ W,
                                              const float* __restrict__ h,
                                              int i0, int ld,
                                              const float* __restrict__ pre) {
  float pA[32], pB[32];
  #pragma unroll
  for (int k = 0; k < 32; ++k) pA[k] = pre[k];
  #pragma unroll
  for (int k = 0; k < 32; ++k) pB[k] = W[(size_t)(i0 + 32 + k) * ld];
  float acc = 0.f;
  #pragma unroll 1
  for (int u = 0; u < N; u += 64) {
    const f32x4* h4 = reinterpret_cast<const f32x4*>(h + i0 + u);
    #pragma unroll
    for (int k = 0; k < 8; ++k) {
      const f32x4 hv = h4[k];
      acc = fmaf(hv.x, pA[4*k+0], acc); acc = fmaf(hv.y, pA[4*k+1], acc);
      acc = fmaf(hv.z, pA[4*k+2], acc); acc = fmaf(hv.w, pA[4*k+3], acc);
    }
    if (u + 64 < N) {
      #pragma unroll
      for (int k = 0; k < 32; ++k) pA[k] = W[(size_t)(i0 + u + 64 + k) * ld];
    }
    #pragma unroll
    for (int k = 0; k < 8; ++k) {
      const f32x4 hv = h4[8 + k];
      acc = fmaf(hv.x, pB[4*k+0], acc); acc = fmaf(hv.y, pB[4*k+1], acc);
      acc = fmaf(hv.z, pB[4*k+2], acc); acc = fmaf(hv.w, pB[4*k+3], acc);
    }
    if (u + 96 < N) {
      #pragma unroll
      for (int k = 0; k < 32; ++k) pB[k] = W[(size_t)(i0 + u + 96 + k) * ld];
    }
  }
  return acc;
}

template<int N>
__device__ __forceinline__ float dotStream(const float* __restrict__ W,
                                           const float* __restrict__ h,
                                           int i0, int ld) {
  float pre[32];
  #pragma unroll
  for (int k = 0; k < 32; ++k) pre[k] = W[(size_t)(i0 + k) * ld];
  return dotStreamPre<N>(W, h, i0, ld, pre);
}

// 32-row dot from a preloaded register array
__device__ __forceinline__ float dot32(const float* __restrict__ w,
                                       const float* __restrict__ h, int i0) {
  float acc = 0.f;
  const f32x4* h4 = reinterpret_cast<const f32x4*>(h + i0);
  #pragma unroll
  for (int k = 0; k < 8; ++k) {
    const f32x4 hv = h4[k];
    acc = fmaf(hv.x, w[4*k+0], acc); acc = fmaf(hv.y, w[4*k+1], acc);
    acc = fmaf(hv.z, w[4*k+2], acc); acc = fmaf(hv.w, w[4*k+3], acc);
  }
  return acc;
}

__global__ __launch_bounds__(256, 1) void mega_kernel(Params p)
{
  const int blk = blockIdx.x;
  const int bb = blk >> 3, sl = blk & 7, tid = threadIdx.x;
  unsigned* flags = p.flags + bb * 256;   // 1 KB apart per batch group
  unsigned target = 0;

  __shared__ __align__(16) float hsh[D];
  __shared__ __align__(16) float ash[128];
  __shared__ float qsh[DH], osh[DH], score[TF], red[4];
  __shared__ float sval[256];
  __shared__ int   sidx[256];
  __shared__ float stage[NSLOT * D];
  __shared__ float kls[NLAYER][TF][DH + 1], vls[NLAYER][TF][DH + 1];
  __shared__ float kcls[NLAYER][NSLOT][DH + 1], vcls[NLAYER][NSLOT][DH + 1];

  // ---- stage boundary: drain stores (syncthreads emits vmcnt(0)), publish flag ----
  auto gsync = [&]() {
    __syncthreads();
    ++target;
    if (tid == 0)
      __hip_atomic_store(flags + sl, target, __ATOMIC_RELAXED, SCOPE_AGENT);
  };
  // ---- wide poll: all 8 flags in 2 loads, single wait (also drains prefetches) ----
  auto gwait = [&]() {
    u32x4 f0, f1;
    for (;;) {
      asm volatile(
        "global_load_dwordx4 %0, %2, off sc0 sc1\n\t"
        "global_load_dwordx4 %1, %2, off offset:16 sc0 sc1\n\t"
        "s_waitcnt vmcnt(0)"
        : "=&v"(f0), "=&v"(f1) : "v"(flags) : "memory");
      if (f0.x >= target && f0.y >= target && f0.z >= target && f0.w >= target &&
          f1.x >= target && f1.y >= target && f1.z >= target && f1.w >= target)
        break;
      __builtin_amdgcn_s_sleep(1);
    }
  };

  auto layernorm = [&](float xv, const float* w, const float* b) -> float {
    const float mean = blockSum(xv, red) * (1.f / D);
    const float dv = xv - mean;
    const float var = blockSum(dv * dv, red) * (1.f / D);
    return dv * (1.f / sqrtf(var + 1e-5f)) * w[tid] + b[tid];
  };

  // ---- fold: 8 coherent loads in one asm block, one RT ----
  auto fold8 = [&](const float* P) -> float {
    const float* a0 = P + (bb * 8 + 0) * D + tid;
    const float* a4 = P + (bb * 8 + 4) * D + tid;
    float s0, s1, s2, s3, s4, s5, s6, s7;
    asm volatile(
      "global_load_dword %0, %8, off sc0 sc1\n\t"
      "global_load_dword %1, %8, off offset:1024 sc0 sc1\n\t"
      "global_load_dword %2, %8, off offset:2048 sc0 sc1\n\t"
      "global_load_dword %3, %8, off offset:3072 sc0 sc1\n\t"
      "global_load_dword %4, %9, off sc0 sc1\n\t"
      "global_load_dword %5, %9, off offset:1024 sc0 sc1\n\t"
      "global_load_dword %6, %9, off offset:2048 sc0 sc1\n\t"
      "global_load_dword %7, %9, off offset:3072 sc0 sc1\n\t"
      "s_waitcnt vmcnt(0)"
      : "=&v"(s0), "=&v"(s1), "=&v"(s2), "=&v"(s3),
        "=&v"(s4), "=&v"(s5), "=&v"(s6), "=&v"(s7)
      : "v"(a0), "v"(a4));
    return ((s0 + s1) + (s2 + s3)) + ((s4 + s5) + (s6 + s7));
  };

  float heldLogit = 0.f;
  int   lastAmax  = 0;

  // ---- tri combine: 8 x dwordx4 in one RT, streamed reg math ----
  auto consume_tri = [&](int row) {
    const float* tb = p.tri + bb * 64;
    f32x4 q0,q1,q2,q3,q4,q5,q6,q7;
    asm volatile(
      "global_load_dwordx4 %0, %8, off sc0 sc1\n\t"
      "global_load_dwordx4 %1, %8, off offset:32 sc0 sc1\n\t"
      "global_load_dwordx4 %2, %8, off offset:64 sc0 sc1\n\t"
      "global_load_dwordx4 %3, %8, off offset:96 sc0 sc1\n\t"
      "global_load_dwordx4 %4, %8, off offset:128 sc0 sc1\n\t"
      "global_load_dwordx4 %5, %8, off offset:160 sc0 sc1\n\t"
      "global_load_dwordx4 %6, %8, off offset:192 sc0 sc1\n\t"
      "global_load_dwordx4 %7, %8, off offset:224 sc0 sc1\n\t"
      "s_waitcnt vmcnt(0)"
      : "=&v"(q0), "=&v"(q1), "=&v"(q2), "=&v"(q3),
        "=&v"(q4), "=&v"(q5), "=&v"(q6), "=&v"(q7)
      : "v"(tb));
    float gm = q0.x;
    gm = fmaxf(gm, q1.x); gm = fmaxf(gm, q2.x); gm = fmaxf(gm, q3.x);
    gm = fmaxf(gm, q4.x); gm = fmaxf(gm, q5.x); gm = fmaxf(gm, q6.x); gm = fmaxf(gm, q7.x);
    float gs = 0.f; float best = -1e30f; int am = 0;
    const f32x4 qa[8] = {q0,q1,q2,q3,q4,q5,q6,q7};
    #pragma unroll
    for (int j = 0; j < 8; ++j) {
      gs += qa[j].y * expf(qa[j].x - gm);
      if (qa[j].x > best) { best = qa[j].x; am = j * 256 + (int)qa[j].z; }  // first-index ties
    }
    const float lse = gm + logf(gs);
    p.out_lp[(bb * GENLEN + row) * VOCAB + sl * 256 + tid] = heldLogit - lse;
    if (sl == 0 && tid == 0)
      p.out_z[bb * VOCAB * GENLEN + am * GENLEN + row] = 1.0f;
    lastAmax = am;
  };

  // ================= init: enc = slots @ W_slot_proj (cols sl*32..) =================
  if (tid < 32) {
    const int c = sl * 32 + tid;
    float acc[NSLOT] = {0.f,0.f,0.f,0.f,0.f,0.f,0.f};
    #pragma unroll 8
    for (int i = 0; i < D; ++i) {
      const float w = p.W_slot_proj[i * D + c];
      #pragma unroll
      for (int s = 0; s < NSLOT; ++s) acc[s] += p.slots[(bb * NSLOT + s) * D + i] * w;
    }
    for (int s = 0; s < NSLOT; ++s) cstore(&p.enc[(bb * NSLOT + s) * D + c], acc[s]);
  }
  gsync(); gwait();

  // ============ init: cross K/V for this block's head -> LDS (block-local) ============
  {
    for (int i = tid; i < NSLOT * D; i += 256) stage[i] = cload(&p.enc[bb * NSLOT * D + i]);
    __syncthreads();
    const int l = tid >> 6, g = tid & 63, c32 = g >> 1, mat = g & 1;
    const float* W = (mat ? p.Wv_c : p.Wk_c) + l * D * D + sl * DH + c32;
    float acc[NSLOT] = {0.f,0.f,0.f,0.f,0.f,0.f,0.f};
    #pragma unroll 8
    for (int i = 0; i < D; ++i) {
      const float w = W[i * D];
      #pragma unroll
      for (int s = 0; s < NSLOT; ++s) acc[s] += stage[s * D + i] * w;
    }
    if (mat) { for (int s = 0; s < NSLOT; ++s) vcls[l][s][c32] = acc[s]; }
    else     { for (int s = 0; s < NSLOT; ++s) kcls[l][s][c32] = acc[s]; }
    __syncthreads();
  }

  float* Pbuf[2] = {p.P0, p.P1};
  int par = 0;
  float x = 0.f;   // replicated residual (identical bits in all 8 slice-blocks)

  // ================================ generation loop ================================
  #pragma unroll 1
  for (int t = 0; t < GENLEN; ++t) {
    #pragma unroll 1
    for (int l = 0; l < NLAYER; ++l) {
      // ------------------------------- SELF-ATTN -------------------------------
      {
        gsync();
        // bounded prefetch (<=64 regs) issued before the poll; poll's vmcnt(0)
        // absorbs the latency for free
        const int mm = tid >> 6, g = tid & 63, c32 = g >> 1, half = g & 1;
        const float* Wqkv = (mm == 0 ? p.Wq_s : (mm == 1 ? p.Wk_s : p.Wv_s))
                          + l * D * D + sl * DH + c32;
        float preq[32];
        if (tid < 192) {
          #pragma unroll
          for (int k = 0; k < 32; ++k) preq[k] = Wqkv[(size_t)(half * 128 + k) * D];
        }
        float wo[32];
        {
          const float* W = p.Wo_s + l * D * D + sl * DH * D + tid;
          #pragma unroll
          for (int k = 0; k < 32; ++k) wo[k] = W[(size_t)k * D];
        }
        gwait();

        if (l == 0) {
          int tok = 0;
          if (t > 0) { consume_tri(t - 1); tok = lastAmax + 1; }
          x = p.dict_emb[tok * D + tid] + p.pe[t * D + tid];
        } else {
          x += fold8(Pbuf[par]);
        }
        const float h = layernorm(x, p.ln_self_w + l * D, p.ln_self_b + l * D);
        if (l == 0) x = h;                    // SLATE quirk (replicated identically)
        hsh[tid] = h;
        __syncthreads();

        if (tid < 192) {
          float acc = dotStreamPre<128>(Wqkv, hsh, half * 128, D, preq);
          acc += __shfl_xor(acc, 1);
          if (half == 0) {
            if (mm == 0)      qsh[c32] = acc * 0.17677669529663689f;   // dh^-0.5
            else if (mm == 1) kls[l][t][c32] = acc;
            else              vls[l][t][c32] = acc;
          }
        }
        __syncthreads();

        if (tid <= t) {
          float a = 0.f;
          #pragma unroll
          for (int r = 0; r < DH; ++r) a += qsh[r] * kls[l][tid][r];
          score[tid] = a;
        }
        __syncthreads();
        if (tid == 0) {
          float mx = -1e30f;
          for (int i = 0; i <= t; ++i) mx = fmaxf(mx, score[i]);
          float s2 = 0.f;
          for (int i = 0; i <= t; ++i) { const float e = expf(score[i] - mx); score[i] = e; s2 += e; }
          const float inv = 1.f / s2;
          for (int i = 0; i <= t; ++i) score[i] *= inv;
        }
        __syncthreads();
        if (tid < DH) {
          float a = 0.f;
          for (int pp = 0; pp <= t; ++pp) a += score[pp] * vls[l][pp][tid];
          osh[tid] = a;
        }
        __syncthreads();
        {
          float a0 = 0.f;
          #pragma unroll
          for (int k = 0; k < 32; ++k) a0 = fmaf(osh[k], wo[k], a0);
          cstore(&Pbuf[par ^ 1][(bb * 8 + sl) * D + tid], a0);
        }
        par ^= 1;
      }

      // ------------------------------- CROSS-ATTN -------------------------------
      {
        gsync();
        const int c32 = tid >> 3, sub = tid & 7;
        float wq[32], woc[32];
        {
          const float* W = p.Wq_c + l * D * D + sl * DH + c32;
          #pragma unroll
          for (int k = 0; k < 32; ++k) wq[k] = W[(size_t)(sub * 32 + k) * D];
        }
        {
          const float* W = p.Wo_c + l * D * D + sl * DH * D + tid;
          #pragma unroll
          for (int k = 0; k < 32; ++k) woc[k] = W[(size_t)k * D];
        }
        gwait();

        x += fold8(Pbuf[par]);
        hsh[tid] = layernorm(x, p.ln_cross_w + l * D, p.ln_cross_b + l * D);
        __syncthreads();

        {
          float acc = dot32(wq, hsh, sub * 32);
          acc += __shfl_xor(acc, 1);
          acc += __shfl_xor(acc, 2);
          acc += __shfl_xor(acc, 4);
          if (sub == 0) qsh[c32] = acc * 0.17677669529663689f;
        }
        __syncthreads();
        if (tid < NSLOT) {
          float a = 0.f;
          #pragma unroll
          for (int r = 0; r < DH; ++r) a += qsh[r] * kcls[l][tid][r];
          score[tid] = a;
        }
        __syncthreads();
        if (tid == 0) {
          float mx = -1e30f;
          for (int i = 0; i < NSLOT; ++i) mx = fmaxf(mx, score[i]);
          float s2 = 0.f;
          for (int i = 0; i < NSLOT; ++i) { const float e = expf(score[i] - mx); score[i] = e; s2 += e; }
          const float inv = 1.f / s2;
          for (int i = 0; i < NSLOT; ++i) score[i] *= inv;
        }
        __syncthreads();
        if (tid < DH) {
          float a = 0.f;
          #pragma unroll
          for (int s = 0; s < NSLOT; ++s) a += score[s] * vcls[l][s][tid];
          osh[tid] = a;
        }
        __syncthreads();
        {
          float a0 = 0.f;
          #pragma unroll
          for (int k = 0; k < 32; ++k) a0 = fmaf(osh[k], woc[k], a0);
          cstore(&Pbuf[par ^ 1][(bb * 8 + sl) * D + tid], a0);
        }
        par ^= 1;
      }

      // ---------------------------------- FFN ----------------------------------
      {
        gsync();
        const int c128 = tid >> 1, half = tid & 1, c = sl * 128 + c128;
        const float* W1p = p.W1 + l * D * FFDIM + c;
        float prew1[32];
        {
          #pragma unroll
          for (int k = 0; k < 32; ++k) prew1[k] = W1p[(size_t)(half * 128 + k) * FFDIM];
        }
        gwait();

        x += fold8(Pbuf[par]);
        hsh[tid] = layernorm(x, p.ln_ffn_w + l * D, p.ln_ffn_b + l * D);
        __syncthreads();

        {
          float acc = dotStreamPre<128>(W1p, hsh, half * 128, FFDIM, prew1);
          acc += __shfl_xor(acc, 1);
          if (half == 0) ash[c128] = fmaxf(acc + p.b1[l * FFDIM + c], 0.f);
        }
        __syncthreads();
        {
          float acc = dotStream<128>(p.W2 + l * FFDIM * D + sl * 128 * D + tid, ash, 0, D);
          if (sl == 0) acc += p.b2[l * D + tid];
          cstore(&Pbuf[par ^ 1][(bb * 8 + sl) * D + tid], acc);
        }
        __syncthreads();
      }
      par ^= 1;
    }

    // --------------------------------- LOGITS ---------------------------------
    {
      gsync();
      const float* Wop = p.W_out + sl * 256 + tid;
      float prewo[32];
      {
        #pragma unroll
        for (int k = 0; k < 32; ++k) prewo[k] = Wop[(size_t)k * VOCAB];
      }
      gwait();

      x += fold8(Pbuf[par]);
      hsh[tid] = layernorm(x, p.ln_f_w, p.ln_f_b);
      __syncthreads();
      heldLogit = dotStreamPre<256>(Wop, hsh, 0, VOCAB, prewo);

      sval[tid] = heldLogit; sidx[tid] = tid;
      __syncthreads();
      for (int s = 128; s; s >>= 1) {
        if (tid < s) {
          float v2 = sval[tid + s]; int i2 = sidx[tid + s];
          if (v2 > sval[tid] || (v2 == sval[tid] && i2 < sidx[tid])) { sval[tid] = v2; sidx[tid] = i2; }
        }
        __syncthreads();
      }
      const float smax = sval[0]; const int sarg = sidx[0];
      __syncthreads();
      const float ssum = blockSum(expf(heldLogit - smax), red);
      if (tid == 0) {
        cstore(&p.tri[(bb * 8 + sl) * 8 + 0], smax);
        cstore(&p.tri[(bb * 8 + sl) * 8 + 1], ssum);
        cstore(&p.tri[(bb * 8 + sl) * 8 + 2], (float)sarg);
      }
      __syncthreads();
    }
  }

  // ------------------------------ final step output ------------------------------
  gsync(); gwait();
  consume_tri(GENLEN - 1);
}

extern "C" void kernel_launch(void* const* d_in, const int* in_sizes, int n_in,
                              void* d_out, int out_size, void* d_ws, size_t ws_size,
                              hipStream_t stream)
{
  Params p;
  const float* const* in = (const float* const*)d_in;
  p.slots = in[0];  p.W_slot_proj = in[1]; p.dict_emb = in[2]; p.pe = in[3];
  p.ln_self_w = in[4];  p.ln_self_b = in[5];
  p.Wq_s = in[6];  p.Wk_s = in[7];  p.Wv_s = in[8];  p.Wo_s = in[9];
  p.ln_cross_w = in[10]; p.ln_cross_b = in[11];
  p.Wq_c = in[12]; p.Wk_c = in[13]; p.Wv_c = in[14]; p.Wo_c = in[15];
  p.ln_ffn_w = in[16]; p.ln_ffn_b = in[17];
  p.W1 = in[18]; p.b1 = in[19]; p.W2 = in[20]; p.b2 = in[21];
  p.ln_f_w = in[22]; p.ln_f_b = in[23]; p.W_out = in[24];

  p.flags = (unsigned*)d_ws;                 // 8 groups x 256 u32 (1 KB each)
  float* ws = (float*)d_ws + BATCH * 256;
  p.enc = ws;  ws += BATCH * NSLOT * D;
  p.P0  = ws;  ws += BATCH * 8 * D;
  p.P1  = ws;  ws += BATCH * 8 * D;
  p.tri = ws;  ws += BATCH * 8 * 8;

  p.out_z  = (float*)d_out;
  p.out_lp = (float*)d_out + BATCH * VOCAB * GENLEN;

  hipMemsetAsync(d_ws, 0, BATCH * 256 * sizeof(unsigned), stream);
  hipMemsetAsync(d_out, 0, (size_t)out_size * sizeof(float), stream);

  mega_kernel<<<64, 256, 0, stream>>>(p);
}

// Round 9
// 1462.559 us; speedup vs baseline: 1.8112x; 1.0301x over previous
//
#include <hip/hip_runtime.h>

#define D       256
#define DH      32
#define FFDIM   1024
#define VOCAB   2048
#define GENLEN  16
#define BATCH   8
#define NSLOT   7
#define TF      17
#define NLAYER  4

#define SCOPE_AGENT __HIP_MEMORY_SCOPE_AGENT

typedef float    f32x4 __attribute__((ext_vector_type(4)));
typedef unsigned u32x4 __attribute__((ext_vector_type(4)));

struct Params {
  const float *slots, *W_slot_proj, *dict_emb, *pe;
  const float *ln_self_w, *ln_self_b, *Wq_s, *Wk_s, *Wv_s, *Wo_s;
  const float *ln_cross_w, *ln_cross_b, *Wq_c, *Wk_c, *Wv_c, *Wo_c;
  const float *ln_ffn_w, *ln_ffn_b, *W1, *b1, *W2, *b2;
  const float *ln_f_w, *ln_f_b, *W_out;
  float *enc, *P0, *P1, *tri;
  unsigned *flags;
  float *out_z, *out_lp;
};

__device__ __forceinline__ float cload(const float* p) {
  return __hip_atomic_load(p, __ATOMIC_RELAXED, SCOPE_AGENT);
}
__device__ __forceinline__ void cstore(float* p, float v) {
  __hip_atomic_store(p, v, __ATOMIC_RELAXED, SCOPE_AGENT);
}

__device__ __forceinline__ float blockSum(float v, float* red) {
  #pragma unroll
  for (int o = 32; o > 0; o >>= 1) v += __shfl_down(v, o);
  const int lane = threadIdx.x & 63, w = threadIdx.x >> 6;
  if (lane == 0) red[w] = v;
  __syncthreads();
  float s = red[0] + red[1] + red[2] + red[3];
  __syncthreads();
  return s;
}

// ---- double-buffered streaming GEMV (live set = 64 regs; round-5 spill lesson) ----
template<int N>
__device__ __forceinline__ float dotStreamPre(const float* __restrict__ W,
                                              const float* __restrict__ h,
                                              int i0, int ld,
                                              const float* __restrict__ pre) {
  float pA[32], pB[32];
  #pragma unroll
  for (int k = 0; k < 32; ++k) pA[k] = pre[k];
  #pragma unroll
  for (int k = 0; k < 32; ++k) pB[k] = W[(size_t)(i0 + 32 + k) * ld];
  float acc = 0.f;
  #pragma unroll 1
  for (int u = 0; u < N; u += 64) {
    const f32x4* h4 = reinterpret_cast<const f32x4*>(h + i0 + u);
    #pragma unroll
    for (int k = 0; k < 8; ++k) {
      const f32x4 hv = h4[k];
      acc = fmaf(hv.x, pA[4*k+0], acc); acc = fmaf(hv.y, pA[4*k+1], acc);
      acc = fmaf(hv.z, pA[4*k+2], acc); acc = fmaf(hv.w, pA[4*k+3], acc);
    }
    if (u + 64 < N) {
      #pragma unroll
      for (int k = 0; k < 32; ++k) pA[k] = W[(size_t)(i0 + u + 64 + k) * ld];
    }
    #pragma unroll
    for (int k = 0; k < 8; ++k) {
      const f32x4 hv = h4[8 + k];
      acc = fmaf(hv.x, pB[4*k+0], acc); acc = fmaf(hv.y, pB[4*k+1], acc);
      acc = fmaf(hv.z, pB[4*k+2], acc); acc = fmaf(hv.w, pB[4*k+3], acc);
    }
    if (u + 96 < N) {
      #pragma unroll
      for (int k = 0; k < 32; ++k) pB[k] = W[(size_t)(i0 + u + 96 + k) * ld];
    }
  }
  return acc;
}

template<int N>
__device__ __forceinline__ float dotStream(const float* __restrict__ W,
                                           const float* __restrict__ h,
                                           int i0, int ld) {
  float pre[32];
  #pragma unroll
  for (int k = 0; k < 32; ++k) pre[k] = W[(size_t)(i0 + k) * ld];
  return dotStreamPre<N>(W, h, i0, ld, pre);
}

__device__ __forceinline__ float dot32(const float* __restrict__ w,
                                       const float* __restrict__ h, int i0) {
  float acc = 0.f;
  const f32x4* h4 = reinterpret_cast<const f32x4*>(h + i0);
  #pragma unroll
  for (int k = 0; k < 8; ++k) {
    const f32x4 hv = h4[k];
    acc = fmaf(hv.x, w[4*k+0], acc); acc = fmaf(hv.y, w[4*k+1], acc);
    acc = fmaf(hv.z, w[4*k+2], acc); acc = fmaf(hv.w, w[4*k+3], acc);
  }
  return acc;
}

__global__ __launch_bounds__(256, 1) void mega_kernel(Params p)
{
  const int blk = blockIdx.x;
  const int bb = blk >> 3, sl = blk & 7, tid = threadIdx.x;
  unsigned* flags = p.flags + bb * 256;
  unsigned target = 0;

  __shared__ __align__(16) float hsh[D];
  __shared__ __align__(16) float ash[128];
  __shared__ float qsh[DH], osh[DH], score[TF], red[4];
  __shared__ float wval[4]; __shared__ int widx[4];
  __shared__ float stage[NSLOT * D];
  __shared__ float kls[NLAYER][TF][DH + 1], vls[NLAYER][TF][DH + 1];
  __shared__ float kcls[NLAYER][NSLOT][DH + 1], vcls[NLAYER][NSLOT][DH + 1];

  auto gsync = [&]() {
    __syncthreads();
    ++target;
    if (tid == 0)
      __hip_atomic_store(flags + sl, target, __ATOMIC_RELAXED, SCOPE_AGENT);
  };
  auto gwait = [&]() {
    u32x4 f0, f1;
    for (;;) {
      asm volatile(
        "global_load_dwordx4 %0, %2, off sc0 sc1\n\t"
        "global_load_dwordx4 %1, %2, off offset:16 sc0 sc1\n\t"
        "s_waitcnt vmcnt(0)"
        : "=&v"(f0), "=&v"(f1) : "v"(flags) : "memory");
      if (f0.x >= target && f0.y >= target && f0.z >= target && f0.w >= target &&
          f1.x >= target && f1.y >= target && f1.z >= target && f1.w >= target)
        break;
      __builtin_amdgcn_s_sleep(1);
    }
  };

  auto layernorm = [&](float xv, const float* w, const float* b) -> float {
    const float mean = blockSum(xv, red) * (1.f / D);
    const float dv = xv - mean;
    const float var = blockSum(dv * dv, red) * (1.f / D);
    return dv * (1.f / sqrtf(var + 1e-5f)) * w[tid] + b[tid];
  };

  auto fold8 = [&](const float* P) -> float {
    const float* a0 = P + (bb * 8 + 0) * D + tid;
    const float* a4 = P + (bb * 8 + 4) * D + tid;
    float s0, s1, s2, s3, s4, s5, s6, s7;
    asm volatile(
      "global_load_dword %0, %8, off sc0 sc1\n\t"
      "global_load_dword %1, %8, off offset:1024 sc0 sc1\n\t"
      "global_load_dword %2, %8, off offset:2048 sc0 sc1\n\t"
      "global_load_dword %3, %8, off offset:3072 sc0 sc1\n\t"
      "global_load_dword %4, %9, off sc0 sc1\n\t"
      "global_load_dword %5, %9, off offset:1024 sc0 sc1\n\t"
      "global_load_dword %6, %9, off offset:2048 sc0 sc1\n\t"
      "global_load_dword %7, %9, off offset:3072 sc0 sc1\n\t"
      "s_waitcnt vmcnt(0)"
      : "=&v"(s0), "=&v"(s1), "=&v"(s2), "=&v"(s3),
        "=&v"(s4), "=&v"(s5), "=&v"(s6), "=&v"(s7)
      : "v"(a0), "v"(a4));
    return ((s0 + s1) + (s2 + s3)) + ((s4 + s5) + (s6 + s7));
  };

  float heldLogit = 0.f;
  int   lastAmax  = 0;

  auto consume_tri = [&](int row) {
    const float* tb = p.tri + bb * 64;
    f32x4 q0,q1,q2,q3,q4,q5,q6,q7;
    asm volatile(
      "global_load_dwordx4 %0, %8, off sc0 sc1\n\t"
      "global_load_dwordx4 %1, %8, off offset:32 sc0 sc1\n\t"
      "global_load_dwordx4 %2, %8, off offset:64 sc0 sc1\n\t"
      "global_load_dwordx4 %3, %8, off offset:96 sc0 sc1\n\t"
      "global_load_dwordx4 %4, %8, off offset:128 sc0 sc1\n\t"
      "global_load_dwordx4 %5, %8, off offset:160 sc0 sc1\n\t"
      "global_load_dwordx4 %6, %8, off offset:192 sc0 sc1\n\t"
      "global_load_dwordx4 %7, %8, off offset:224 sc0 sc1\n\t"
      "s_waitcnt vmcnt(0)"
      : "=&v"(q0), "=&v"(q1), "=&v"(q2), "=&v"(q3),
        "=&v"(q4), "=&v"(q5), "=&v"(q6), "=&v"(q7)
      : "v"(tb));
    float gm = q0.x;
    gm = fmaxf(gm, q1.x); gm = fmaxf(gm, q2.x); gm = fmaxf(gm, q3.x);
    gm = fmaxf(gm, q4.x); gm = fmaxf(gm, q5.x); gm = fmaxf(gm, q6.x); gm = fmaxf(gm, q7.x);
    float gs = 0.f; float best = -1e30f; int am = 0;
    const f32x4 qa[8] = {q0,q1,q2,q3,q4,q5,q6,q7};
    #pragma unroll
    for (int j = 0; j < 8; ++j) {
      gs += qa[j].y * expf(qa[j].x - gm);
      if (qa[j].x > best) { best = qa[j].x; am = j * 256 + (int)qa[j].z; }  // first-index ties
    }
    const float lse = gm + logf(gs);
    p.out_lp[(bb * GENLEN + row) * VOCAB + sl * 256 + tid] = heldLogit - lse;
    if (sl == 0 && tid == 0)
      p.out_z[bb * VOCAB * GENLEN + am * GENLEN + row] = 1.0f;
    lastAmax = am;
  };

  // ---- zero K/V LDS (rows > t are read with 0-weights; garbage*0 would NaN) ----
  for (int i = tid; i < NLAYER * TF * (DH + 1); i += 256) {
    (&kls[0][0][0])[i] = 0.f;
    (&vls[0][0][0])[i] = 0.f;
  }

  // ================= init: enc = slots @ W_slot_proj (cols sl*32..) =================
  if (tid < 32) {
    const int c = sl * 32 + tid;
    float acc[NSLOT] = {0.f,0.f,0.f,0.f,0.f,0.f,0.f};
    #pragma unroll 8
    for (int i = 0; i < D; ++i) {
      const float w = p.W_slot_proj[i * D + c];
      #pragma unroll
      for (int s = 0; s < NSLOT; ++s) acc[s] += p.slots[(bb * NSLOT + s) * D + i] * w;
    }
    for (int s = 0; s < NSLOT; ++s) cstore(&p.enc[(bb * NSLOT + s) * D + c], acc[s]);
  }
  gsync(); gwait();

  // ============ init: cross K/V for this block's head -> LDS (block-local) ============
  {
    for (int i = tid; i < NSLOT * D; i += 256) stage[i] = cload(&p.enc[bb * NSLOT * D + i]);
    __syncthreads();
    const int l = tid >> 6, g = tid & 63, c32 = g >> 1, mat = g & 1;
    const float* W = (mat ? p.Wv_c : p.Wk_c) + l * D * D + sl * DH + c32;
    float acc[NSLOT] = {0.f,0.f,0.f,0.f,0.f,0.f,0.f};
    #pragma unroll 8
    for (int i = 0; i < D; ++i) {
      const float w = W[i * D];
      #pragma unroll
      for (int s = 0; s < NSLOT; ++s) acc[s] += stage[s * D + i] * w;
    }
    if (mat) { for (int s = 0; s < NSLOT; ++s) vcls[l][s][c32] = acc[s]; }
    else     { for (int s = 0; s < NSLOT; ++s) kcls[l][s][c32] = acc[s]; }
    __syncthreads();
  }

  float* Pbuf[2] = {p.P0, p.P1};
  int par = 0;
  float x = 0.f;   // replicated residual (identical bits in all 8 slice-blocks)

  // ================================ generation loop ================================
  #pragma unroll 1
  for (int t = 0; t < GENLEN; ++t) {
    #pragma unroll 1
    for (int l = 0; l < NLAYER; ++l) {
      // ------------------------------- SELF-ATTN -------------------------------
      {
        gsync();
        const int mm = tid >> 6, g = tid & 63, c32 = g >> 1, half = g & 1;
        const float* Wqkv = (mm == 0 ? p.Wq_s : (mm == 1 ? p.Wk_s : p.Wv_s))
                          + l * D * D + sl * DH + c32;
        float preq[32];
        if (tid < 192) {
          #pragma unroll
          for (int k = 0; k < 32; ++k) preq[k] = Wqkv[(size_t)(half * 128 + k) * D];
        }
        float wo[32];
        {
          const float* W = p.Wo_s + l * D * D + sl * DH * D + tid;
          #pragma unroll
          for (int k = 0; k < 32; ++k) wo[k] = W[(size_t)k * D];
        }
        gwait();

        if (l == 0) {
          int tok = 0;
          if (t > 0) { consume_tri(t - 1); tok = lastAmax + 1; }
          x = p.dict_emb[tok * D + tid] + p.pe[t * D + tid];
        } else {
          x += fold8(Pbuf[par]);
        }
        const float h = layernorm(x, p.ln_self_w + l * D, p.ln_self_b + l * D);
        if (l == 0) x = h;                    // SLATE quirk (replicated identically)
        hsh[tid] = h;
        __syncthreads();

        if (tid < 192) {
          float acc = dotStreamPre<128>(Wqkv, hsh, half * 128, D, preq);
          acc += __shfl_xor(acc, 1);
          if (half == 0) {
            if (mm == 0)      qsh[c32] = acc * 0.17677669529663689f;   // dh^-0.5
            else if (mm == 1) kls[l][t][c32] = acc;
            else              vls[l][t][c32] = acc;
          }
        }
        __syncthreads();

        // ---- wave-parallel softmax: lane p of wave 0 owns position p ----
        if (tid < 64) {
          float s = -1e30f;
          if (tid <= t) {
            float a = 0.f;
            #pragma unroll
            for (int r = 0; r < DH; ++r) a += qsh[r] * kls[l][tid][r];
            s = a;
          }
          float m = s;
          #pragma unroll
          for (int o = 32; o > 0; o >>= 1) m = fmaxf(m, __shfl_xor(m, o));
          const float e = (tid <= t) ? expf(s - m) : 0.f;
          float sum = e;
          #pragma unroll
          for (int o = 32; o > 0; o >>= 1) sum += __shfl_xor(sum, o);
          const float inv = 1.f / sum;
          if (tid < TF) score[tid] = e * inv;     // zeros for t < pos < TF
        }
        __syncthreads();
        // ---- PV: static TF bound, zero weights past t contribute exactly +0 ----
        if (tid < DH) {
          float a = 0.f;
          #pragma unroll
          for (int pp = 0; pp < TF; ++pp) a = fmaf(score[pp], vls[l][pp][tid], a);
          osh[tid] = a;
        }
        __syncthreads();
        {
          float a0 = 0.f;
          #pragma unroll
          for (int k = 0; k < 32; ++k) a0 = fmaf(osh[k], wo[k], a0);
          cstore(&Pbuf[par ^ 1][(bb * 8 + sl) * D + tid], a0);
        }
        par ^= 1;
      }

      // ------------------------------- CROSS-ATTN -------------------------------
      {
        gsync();
        const int c32 = tid >> 3, sub = tid & 7;
        float wq[32], woc[32];
        {
          const float* W = p.Wq_c + l * D * D + sl * DH + c32;
          #pragma unroll
          for (int k = 0; k < 32; ++k) wq[k] = W[(size_t)(sub * 32 + k) * D];
        }
        {
          const float* W = p.Wo_c + l * D * D + sl * DH * D + tid;
          #pragma unroll
          for (int k = 0; k < 32; ++k) woc[k] = W[(size_t)k * D];
        }
        gwait();

        x += fold8(Pbuf[par]);
        hsh[tid] = layernorm(x, p.ln_cross_w + l * D, p.ln_cross_b + l * D);
        __syncthreads();

        {
          float acc = dot32(wq, hsh, sub * 32);
          acc += __shfl_xor(acc, 1);
          acc += __shfl_xor(acc, 2);
          acc += __shfl_xor(acc, 4);
          if (sub == 0) qsh[c32] = acc * 0.17677669529663689f;
        }
        __syncthreads();

        // ---- wave-parallel softmax over 7 slots ----
        if (tid < 64) {
          float s = -1e30f;
          if (tid < NSLOT) {
            float a = 0.f;
            #pragma unroll
            for (int r = 0; r < DH; ++r) a += qsh[r] * kcls[l][tid][r];
            s = a;
          }
          float m = s;
          #pragma unroll
          for (int o = 32; o > 0; o >>= 1) m = fmaxf(m, __shfl_xor(m, o));
          const float e = (tid < NSLOT) ? expf(s - m) : 0.f;
          float sum = e;
          #pragma unroll
          for (int o = 32; o > 0; o >>= 1) sum += __shfl_xor(sum, o);
          const float inv = 1.f / sum;
          if (tid < NSLOT) score[tid] = e * inv;
        }
        __syncthreads();
        if (tid < DH) {
          float a = 0.f;
          #pragma unroll
          for (int s = 0; s < NSLOT; ++s) a = fmaf(score[s], vcls[l][s][tid], a);
          osh[tid] = a;
        }
        __syncthreads();
        {
          float a0 = 0.f;
          #pragma unroll
          for (int k = 0; k < 32; ++k) a0 = fmaf(osh[k], woc[k], a0);
          cstore(&Pbuf[par ^ 1][(bb * 8 + sl) * D + tid], a0);
        }
        par ^= 1;
      }

      // ---------------------------------- FFN ----------------------------------
      {
        gsync();
        const int c128 = tid >> 1, half = tid & 1, c = sl * 128 + c128;
        const float* W1p = p.W1 + l * D * FFDIM + c;
        float prew1[32];
        {
          #pragma unroll
          for (int k = 0; k < 32; ++k) prew1[k] = W1p[(size_t)(half * 128 + k) * FFDIM];
        }
        gwait();

        x += fold8(Pbuf[par]);
        hsh[tid] = layernorm(x, p.ln_ffn_w + l * D, p.ln_ffn_b + l * D);
        __syncthreads();

        {
          float acc = dotStreamPre<128>(W1p, hsh, half * 128, FFDIM, prew1);
          acc += __shfl_xor(acc, 1);
          if (half == 0) ash[c128] = fmaxf(acc + p.b1[l * FFDIM + c], 0.f);
        }
        __syncthreads();
        {
          float acc = dotStream<128>(p.W2 + l * FFDIM * D + sl * 128 * D + tid, ash, 0, D);
          if (sl == 0) acc += p.b2[l * D + tid];
          cstore(&Pbuf[par ^ 1][(bb * 8 + sl) * D + tid], acc);
        }
        __syncthreads();
      }
      par ^= 1;
    }

    // --------------------------------- LOGITS ---------------------------------
    {
      gsync();
      const float* Wop = p.W_out + sl * 256 + tid;
      float prewo[32];
      {
        #pragma unroll
        for (int k = 0; k < 32; ++k) prewo[k] = Wop[(size_t)k * VOCAB];
      }
      gwait();

      x += fold8(Pbuf[par]);
      hsh[tid] = layernorm(x, p.ln_f_w, p.ln_f_b);
      __syncthreads();
      heldLogit = dotStreamPre<256>(Wop, hsh, 0, VOCAB, prewo);

      // ---- wave-level max/argmax (first-index ties), one LDS combine ----
      {
        float v = heldLogit; int idx = tid;
        #pragma unroll
        for (int o = 32; o > 0; o >>= 1) {
          const float v2 = __shfl_xor(v, o);
          const int   i2 = __shfl_xor(idx, o);
          if (v2 > v || (v2 == v && i2 < idx)) { v = v2; idx = i2; }
        }
        const int w = tid >> 6;
        if ((tid & 63) == 0) { wval[w] = v; widx[w] = idx; }
      }
      __syncthreads();
      float smax = wval[0]; int sarg = widx[0];
      #pragma unroll
      for (int j = 1; j < 4; ++j)
        if (wval[j] > smax || (wval[j] == smax && widx[j] < sarg)) { smax = wval[j]; sarg = widx[j]; }
      const float ssum = blockSum(expf(heldLogit - smax), red);
      if (tid == 0) {
        cstore(&p.tri[(bb * 8 + sl) * 8 + 0], smax);
        cstore(&p.tri[(bb * 8 + sl) * 8 + 1], ssum);
        cstore(&p.tri[(bb * 8 + sl) * 8 + 2], (float)sarg);
      }
      __syncthreads();
    }
  }

  // ------------------------------ final step output ------------------------------
  gsync(); gwait();
  consume_tri(GENLEN - 1);
}

extern "C" void kernel_launch(void* const* d_in, const int* in_sizes, int n_in,
                              void* d_out, int out_size, void* d_ws, size_t ws_size,
                              hipStream_t stream)
{
  Params p;
  const float* const* in = (const float* const*)d_in;
  p.slots = in[0];  p.W_slot_proj = in[1]; p.dict_emb = in[2]; p.pe = in[3];
  p.ln_self_w = in[4];  p.ln_self_b = in[5];
  p.Wq_s = in[6];  p.Wk_s = in[7];  p.Wv_s = in[8];  p.Wo_s = in[9];
  p.ln_cross_w = in[10]; p.ln_cross_b = in[11];
  p.Wq_c = in[12]; p.Wk_c = in[13]; p.Wv_c = in[14]; p.Wo_c = in[15];
  p.ln_ffn_w = in[16]; p.ln_ffn_b = in[17];
  p.W1 = in[18]; p.b1 = in[19]; p.W2 = in[20]; p.b2 = in[21];
  p.ln_f_w = in[22]; p.ln_f_b = in[23]; p.W_out = in[24];

  p.flags = (unsigned*)d_ws;                 // 8 groups x 256 u32 (1 KB each)
  float* ws = (float*)d_ws + BATCH * 256;
  p.enc = ws;  ws += BATCH * NSLOT * D;
  p.P0  = ws;  ws += BATCH * 8 * D;
  p.P1  = ws;  ws += BATCH * 8 * D;
  p.tri = ws;  ws += BATCH * 8 * 8;

  p.out_z  = (float*)d_out;
  p.out_lp = (float*)d_out + BATCH * VOCAB * GENLEN;

  hipMemsetAsync(d_ws, 0, BATCH * 256 * sizeof(unsigned), stream);
  hipMemsetAsync(d_out, 0, (size_t)out_size * sizeof(float), stream);

  mega_kernel<<<64, 256, 0, stream>>>(p);
}